// Round 5
// baseline (580.460 us; speedup 1.0000x reference)
//
#include <hip/hip_runtime.h>
#include <hip/hip_fp16.h>

#define N_NODES   100000
#define N_CLASSES 16
#define N_EDGES   3200000

// ---- fused geometry: 256 blocks x 1024 threads, 100 KB LDS -> 1 block/CU ----
#define R2        2
#define NPR2      50000                 // nodes per range (fp16 hist)
#define DYN2      (NPR2 * 2)            // 100000 B dynamic LDS
#define S2        128                   // slices; block b: s=b&127, r=b>>7
#define EPS2      25000                 // 128*25000 == N_EDGES exactly
#define GRID      256
#define B_TH      1024
#define TOTAL_TH  (GRID * B_TH)         // 262144
#define NQUADS    (N_EDGES / 4)         // 800000

// ---- non-fused fallback (R4 pipeline) ----
#define R_ST      8
#define NPR_ST    12500
#define S_ST      64
#define EPS_ST    50000
#define B_DEG     1024
#define KE        8
#define EDGE_BLOCKS ((N_EDGES / KE + 255) / 256)   // 1563

// ===================== fp8 e4m3 helpers (verified rounds 0-4) =====================

__device__ __forceinline__ unsigned f2fp8(float f) {
    unsigned u = __float_as_uint(f);
    unsigned s = (u >> 24) & 0x80u;
    float g = fabsf(f) * 0x1p-120f;
    unsigned gu = __float_as_uint(g);
    gu += 0x7FFFFu + ((gu >> 20) & 1u);       // RNE at bit 20
    unsigned mag = gu >> 20;
    if (mag > 0x7Eu) mag = 0x7Eu;             // clamp to 448
    return s | mag;
}

__device__ __forceinline__ float fp82f(unsigned b) {
    unsigned u = ((b & 0x80u) << 24) | ((b & 0x7Fu) << 20);
    return __uint_as_float(u) * 0x1p120f;
}

#if defined(__has_builtin)
#if __has_builtin(__builtin_amdgcn_cvt_pk_f32_fp8)
#define HAVE_HW_FP8 1
#endif
#endif

#ifdef HAVE_HW_FP8
typedef float v2f __attribute__((ext_vector_type(2)));
__device__ __forceinline__ float ssd4(unsigned a, unsigned b) {
    v2f a0 = __builtin_amdgcn_cvt_pk_f32_fp8((int)a, false);
    v2f a1 = __builtin_amdgcn_cvt_pk_f32_fp8((int)a, true);
    v2f b0 = __builtin_amdgcn_cvt_pk_f32_fp8((int)b, false);
    v2f b1 = __builtin_amdgcn_cvt_pk_f32_fp8((int)b, true);
    float d0 = a0.x - b0.x;
    float d1 = a0.y - b0.y;
    float d2 = a1.x - b1.x;
    float d3 = a1.y - b1.y;
    return d0 * d0 + d1 * d1 + d2 * d2 + d3 * d3;
}
#else
__device__ __forceinline__ float ssd4(unsigned a, unsigned b) {
    float s = 0.0f;
#pragma unroll
    for (int i = 0; i < 4; ++i) {
        float va = fp82f((a >> (8 * i)) & 0xFFu);
        float vb = fp82f((b >> (8 * i)) & 0xFFu);
        float d = va - vb;
        s += d * d;
    }
    return s;
}
#endif

__device__ __forceinline__ float ssd16(uint4 A, uint4 B) {
    return ssd4(A.x, B.x) + ssd4(A.y, B.y) + ssd4(A.z, B.z) + ssd4(A.w, B.w);
}

__device__ __forceinline__ void pk_hist_add(unsigned lds_base, int t, float wv) {
    const unsigned hb   = (unsigned)__half_as_ushort(__float2half(wv));
    const unsigned data = (t & 1) ? (hb << 16) : hb;
    const unsigned addr = lds_base + (unsigned)(t >> 1) * 4u;
    asm volatile("ds_pk_add_f16 %0, %1" :: "v"(addr), "v"(data) : "memory");
}

// ===================== manual grid barrier (G16: device-scope fence+atomic) =====
// All GRID blocks are co-resident by construction (100 KB LDS -> 1 block/CU,
// grid == 256 == CU count), so spin-wait is deadlock-free. Bounded spin as a
// safety valve (wrong-answer fail instead of hang if residency ever breaks).

__device__ __forceinline__ void grid_barrier(int* cnt) {
    __threadfence();                          // release: drain + L2 writeback
    __syncthreads();
    if (threadIdx.x == 0) {
        atomicAdd(cnt, 1);                    // device scope
        int polls = 0;
        while (__hip_atomic_load(cnt, __ATOMIC_ACQUIRE, __HIP_MEMORY_SCOPE_AGENT)
                   < GRID && polls < 100000000) {
            __builtin_amdgcn_s_sleep(4);
            ++polls;
        }
    }
    __syncthreads();
    __threadfence();                          // acquire
}

// ===================== init: zero barrier counters (ws is poisoned) ==========

__global__ __launch_bounds__(64) void lap_init(int* __restrict__ cnt) {
    if (threadIdx.x < 4) cnt[threadIdx.x] = 0;
}

// ===================== THE fused kernel ======================================

__global__ __launch_bounds__(B_TH) void lap_fused(
        const int* __restrict__ rows, const int* __restrict__ cols,
        const float* __restrict__ w,  const float* __restrict__ y,
        __half* __restrict__ shadows, unsigned char* __restrict__ yhat,
        float* __restrict__ partial,  int* __restrict__ cnt,
        float* __restrict__ out) {
    extern __shared__ __align__(16) unsigned char histb[];
    const int b   = blockIdx.x;
    const int tid = threadIdx.x;

    // -------- phase 1: degree histogram (== lap_degree_r2) --------
    {
        const int s  = b & (S2 - 1);
        const int r  = b >> 7;
        const int lo = r * NPR2;
        const unsigned lds_base = (unsigned)(size_t)histb;

        uint4* h4 = (uint4*)histb;                       // 6250 uint4
        for (int i = tid; i < DYN2 / 16; i += B_TH)
            h4[i] = make_uint4(0u, 0u, 0u, 0u);
        __syncthreads();

        const int base = s * EPS2;
        for (int g = tid; g < EPS2 / 4; g += B_TH) {
            const int e = base + g * 4;
            int4   r4 = *(const int4*)(rows + e);
            float4 w4 = *(const float4*)(w + e);
            int t;
            t = r4.x - lo; if ((unsigned)t < (unsigned)NPR2) pk_hist_add(lds_base, t, w4.x);
            t = r4.y - lo; if ((unsigned)t < (unsigned)NPR2) pk_hist_add(lds_base, t, w4.y);
            t = r4.z - lo; if ((unsigned)t < (unsigned)NPR2) pk_hist_add(lds_base, t, w4.z);
            t = r4.w - lo; if ((unsigned)t < (unsigned)NPR2) pk_hist_add(lds_base, t, w4.w);
        }
        __syncthreads();

        uint4* dst = (uint4*)(shadows + (size_t)s * N_NODES + lo);
        for (int i = tid; i < DYN2 / 16; i += B_TH) dst[i] = h4[i];
    }

    grid_barrier(&cnt[0]);

    // -------- phase 2: shadow reduce (2 thr/node, 64 slices each) -> fp8 yhat --------
    {
        const int gtid = b * B_TH + tid;
        const int node = gtid >> 1;
        const int half = gtid & 1;
        float a0 = 0.f, a1 = 0.f, a2 = 0.f, a3 = 0.f;
        if (node < N_NODES) {
            const __half* p = shadows + node;
            const int sb = half * 64;
#pragma unroll
            for (int j = 0; j < 64; j += 4) {
                a0 += __half2float(p[(size_t)(sb + j)     * N_NODES]);
                a1 += __half2float(p[(size_t)(sb + j + 1) * N_NODES]);
                a2 += __half2float(p[(size_t)(sb + j + 2) * N_NODES]);
                a3 += __half2float(p[(size_t)(sb + j + 3) * N_NODES]);
            }
        }
        float deg = (a0 + a1) + (a2 + a3);
        deg += __shfl_xor(deg, 1, 64);               // combine node's two halves
        if (node < N_NODES && half == 0) {
            const float inv = rsqrtf(deg);
            const float4* yr = (const float4*)(y + (size_t)node * N_CLASSES);
            uint4 o;
            unsigned* op = (unsigned*)&o;
#pragma unroll
            for (int j = 0; j < 4; ++j) {
                float4 v = yr[j];
                op[j] =  f2fp8(v.x * inv)
                      | (f2fp8(v.y * inv) << 8)
                      | (f2fp8(v.z * inv) << 16)
                      | (f2fp8(v.w * inv) << 24);
            }
            *(uint4*)(yhat + (size_t)node * N_CLASSES) = o;
        }
    }

    grid_barrier(&cnt[1]);

    // -------- phase 3: edge pass (grid-stride quads) --------
    float local = 0.0f;
    {
        const int gtid = b * B_TH + tid;
        for (int q = gtid; q < NQUADS; q += TOTAL_TH) {       // <= 4 iters
            const int e = q * 4;
            int4   r4 = *(const int4*)(rows + e);
            int4   c4 = *(const int4*)(cols + e);
            float4 w4 = *(const float4*)(w + e);
            uint4 Ax = *(const uint4*)(yhat + (size_t)r4.x * N_CLASSES);
            uint4 Bx = *(const uint4*)(yhat + (size_t)c4.x * N_CLASSES);
            uint4 Ay = *(const uint4*)(yhat + (size_t)r4.y * N_CLASSES);
            uint4 By = *(const uint4*)(yhat + (size_t)c4.y * N_CLASSES);
            uint4 Az = *(const uint4*)(yhat + (size_t)r4.z * N_CLASSES);
            uint4 Bz = *(const uint4*)(yhat + (size_t)c4.z * N_CLASSES);
            uint4 Aw = *(const uint4*)(yhat + (size_t)r4.w * N_CLASSES);
            uint4 Bw = *(const uint4*)(yhat + (size_t)c4.w * N_CLASSES);
            local += w4.x * sqrtf(ssd16(Ax, Bx))
                   + w4.y * sqrtf(ssd16(Ay, By))
                   + w4.z * sqrtf(ssd16(Az, Bz))
                   + w4.w * sqrtf(ssd16(Aw, Bw));
        }
    }

    // block partial
#pragma unroll
    for (int off = 32; off > 0; off >>= 1) local += __shfl_down(local, off, 64);
    __shared__ float smr[16];
    const int lane = tid & 63;
    const int wid  = tid >> 6;
    if (lane == 0) smr[wid] = local;
    __syncthreads();
    if (tid == 0) {
        float t = 0.0f;
#pragma unroll
        for (int i = 0; i < 16; ++i) t += smr[i];
        partial[b] = t;
    }

    // -------- last-block final reduce --------
    __threadfence();
    __shared__ int amLast;
    if (tid == 0) amLast = (atomicAdd(&cnt[2], 1) == GRID - 1);
    __syncthreads();
    if (amLast) {
        __threadfence();
        float v = 0.0f;
        if (tid < GRID) v = partial[tid];
        if (tid < GRID) {
#pragma unroll
            for (int off = 32; off > 0; off >>= 1) v += __shfl_down(v, off, 64);
            if ((tid & 63) == 0) smr[tid >> 6] = v;   // waves 0..3
        }
        __syncthreads();
        if (tid == 0)
            out[0] = (smr[0] + smr[1] + smr[2] + smr[3]) * (1.0f / (float)N_EDGES);
    }
}

// ===================== non-fused fallback pipeline (R4, verified) =============

__global__ __launch_bounds__(B_DEG) void lap_degree_static(
        const int* __restrict__ rows, const float* __restrict__ w,
        __half* __restrict__ shadows) {
    __shared__ float hist[NPR_ST];
    const int r  = blockIdx.x & (R_ST - 1);
    const int s  = blockIdx.x >> 3;
    const int lo = r * NPR_ST;

    for (int i = threadIdx.x; i < NPR_ST; i += B_DEG) hist[i] = 0.0f;
    __syncthreads();

    const int base = s * EPS_ST;
    for (int g = threadIdx.x; g < EPS_ST / 4; g += B_DEG) {
        const int e = base + g * 4;
        int4   r4 = *(const int4*)(rows + e);
        float4 w4 = *(const float4*)(w + e);
        int t;
        t = r4.x - lo; if ((unsigned)t < (unsigned)NPR_ST) atomicAdd(&hist[t], w4.x);
        t = r4.y - lo; if ((unsigned)t < (unsigned)NPR_ST) atomicAdd(&hist[t], w4.y);
        t = r4.z - lo; if ((unsigned)t < (unsigned)NPR_ST) atomicAdd(&hist[t], w4.z);
        t = r4.w - lo; if ((unsigned)t < (unsigned)NPR_ST) atomicAdd(&hist[t], w4.w);
    }
    __syncthreads();

    __half* dst = shadows + (size_t)s * N_NODES + lo;
    for (int i = threadIdx.x; i < NPR_ST; i += B_DEG) dst[i] = __float2half(hist[i]);
}

__global__ __launch_bounds__(256) void lap_yhat_par(
        const __half* __restrict__ shadows,
        const float* __restrict__ y,
        unsigned char* __restrict__ yhat, int S) {
    const int lane = threadIdx.x & 63;
    const int wv   = threadIdx.x >> 6;
    const int n    = blockIdx.x * 64 + lane;

    float a0 = 0.0f, a1 = 0.0f, a2 = 0.0f, a3 = 0.0f;
    if (n < N_NODES) {
        const __half* p = shadows + n;
        int s = wv;
        for (; s + 12 < S; s += 16) {
            a0 += __half2float(p[(size_t)(s)      * N_NODES]);
            a1 += __half2float(p[(size_t)(s + 4)  * N_NODES]);
            a2 += __half2float(p[(size_t)(s + 8)  * N_NODES]);
            a3 += __half2float(p[(size_t)(s + 12) * N_NODES]);
        }
        for (; s < S; s += 4)
            a0 += __half2float(p[(size_t)s * N_NODES]);
    }

    __shared__ float sm[4][64];
    sm[wv][lane] = (a0 + a1) + (a2 + a3);
    __syncthreads();

    if (wv == 0 && n < N_NODES) {
        const float deg = (sm[0][lane] + sm[1][lane]) + (sm[2][lane] + sm[3][lane]);
        const float inv = rsqrtf(deg);
        const float4* yr = (const float4*)(y + (size_t)n * N_CLASSES);
        uint4 o;
        unsigned* op = (unsigned*)&o;
#pragma unroll
        for (int j = 0; j < 4; ++j) {
            float4 v = yr[j];
            op[j] =  f2fp8(v.x * inv)
                  | (f2fp8(v.y * inv) << 8)
                  | (f2fp8(v.z * inv) << 16)
                  | (f2fp8(v.w * inv) << 24);
        }
        *(uint4*)(yhat + (size_t)n * N_CLASSES) = o;
    }
}

__global__ void lap_edge_fp8(const int* __restrict__ rows,
                             const int* __restrict__ cols,
                             const float* __restrict__ w,
                             const unsigned char* __restrict__ yhat,
                             float* __restrict__ partial) {
    const int tid = blockIdx.x * blockDim.x + threadIdx.x;
    const long e0 = (long)tid * KE;
    float local = 0.0f;
    if (e0 < N_EDGES) {
        int4   ra = *(const int4*)(rows + e0);
        int4   rb = *(const int4*)(rows + e0 + 4);
        int4   ca = *(const int4*)(cols + e0);
        int4   cb = *(const int4*)(cols + e0 + 4);
        float4 wa = *(const float4*)(w + e0);
        float4 wb = *(const float4*)(w + e0 + 4);

        const int ri[KE] = {ra.x, ra.y, ra.z, ra.w, rb.x, rb.y, rb.z, rb.w};
        const int ci[KE] = {ca.x, ca.y, ca.z, ca.w, cb.x, cb.y, cb.z, cb.w};
        const float wv[KE] = {wa.x, wa.y, wa.z, wa.w, wb.x, wb.y, wb.z, wb.w};

        uint4 A[KE], B[KE];
#pragma unroll
        for (int k = 0; k < KE; ++k) {
            A[k] = *(const uint4*)(yhat + (size_t)ri[k] * N_CLASSES);
            B[k] = *(const uint4*)(yhat + (size_t)ci[k] * N_CLASSES);
        }
#pragma unroll
        for (int k = 0; k < KE; ++k)
            local += wv[k] * sqrtf(ssd16(A[k], B[k]));
    }
#pragma unroll
    for (int off = 32; off > 0; off >>= 1) local += __shfl_down(local, off, 64);
    __shared__ float sm[4];
    const int lane = threadIdx.x & 63;
    const int wid  = threadIdx.x >> 6;
    if (lane == 0) sm[wid] = local;
    __syncthreads();
    if (threadIdx.x == 0)
        partial[blockIdx.x] = sm[0] + sm[1] + sm[2] + sm[3];
}

__global__ __launch_bounds__(1024) void lap_reduce(
        const float* __restrict__ partial, float* __restrict__ out) {
    float local = 0.0f;
    for (int i = threadIdx.x; i < EDGE_BLOCKS; i += 1024) local += partial[i];
#pragma unroll
    for (int off = 32; off > 0; off >>= 1) local += __shfl_down(local, off, 64);
    __shared__ float sm[16];
    const int lane = threadIdx.x & 63;
    const int wid  = threadIdx.x >> 6;
    if (lane == 0) sm[wid] = local;
    __syncthreads();
    if (threadIdx.x == 0) {
        float t = 0.0f;
#pragma unroll
        for (int i = 0; i < 16; ++i) t += sm[i];
        out[0] = t * (1.0f / (float)N_EDGES);
    }
}

// ===================== low fallback (tiny ws) =====================

__global__ void lap_degree_kernel(const int* __restrict__ rows,
                                  const float* __restrict__ w,
                                  float* __restrict__ degree) {
    int i = blockIdx.x * blockDim.x + threadIdx.x;
    if (i < N_EDGES) atomicAdd(&degree[rows[i]], w[i]);
}

__global__ void lap_invd_kernel(const float* __restrict__ degree,
                                float* __restrict__ invd) {
    int i = blockIdx.x * blockDim.x + threadIdx.x;
    if (i < N_NODES) invd[i] = rsqrtf(degree[i]);
}

__global__ void lap_edge_kernel(const int* __restrict__ rows,
                                const int* __restrict__ cols,
                                const float* __restrict__ w,
                                const float* __restrict__ y,
                                const float* __restrict__ invd,
                                float* __restrict__ out) {
    int i = blockIdx.x * blockDim.x + threadIdx.x;
    float local = 0.0f;
    if (i < N_EDGES) {
        int r = rows[i], c = cols[i];
        float dr = invd[r], dc = invd[c];
        const float4* yr = (const float4*)(y + (size_t)r * N_CLASSES);
        const float4* yc = (const float4*)(y + (size_t)c * N_CLASSES);
        float s = 0.0f;
#pragma unroll
        for (int j = 0; j < N_CLASSES / 4; ++j) {
            float4 a = yr[j], b = yc[j];
            float d0 = a.x * dr - b.x * dc;
            float d1 = a.y * dr - b.y * dc;
            float d2 = a.z * dr - b.z * dc;
            float d3 = a.w * dr - b.w * dc;
            s += d0 * d0 + d1 * d1 + d2 * d2 + d3 * d3;
        }
        local = w[i] * sqrtf(s);
    }
#pragma unroll
    for (int off = 32; off > 0; off >>= 1) local += __shfl_down(local, off, 64);
    __shared__ float sm[4];
    int lane = threadIdx.x & 63, wid = threadIdx.x >> 6;
    if (lane == 0) sm[wid] = local;
    __syncthreads();
    if (threadIdx.x == 0)
        atomicAdd(out, (sm[0] + sm[1] + sm[2] + sm[3]) * (1.0f / (float)N_EDGES));
}

// ===================== launch =====================

extern "C" void kernel_launch(void* const* d_in, const int* in_sizes, int n_in,
                              void* d_out, int out_size, void* d_ws, size_t ws_size,
                              hipStream_t stream) {
    const int*   edge_index = (const int*)d_in[0];   // [rows | cols]
    const float* w          = (const float*)d_in[1];
    const float* y          = (const float*)d_in[2];
    float*       out        = (float*)d_out;

    const int* rows = edge_index;
    const int* cols = edge_index + N_EDGES;
    const int  B = 256;

    // ws layout: [shadows 25.6MB][yhat 1.6MB][partial 1563*4B][cnt 4*4B]
    const size_t sh_bytes   = (size_t)S2 * N_NODES * sizeof(__half);
    const size_t yh_bytes   = (size_t)N_NODES * N_CLASSES;
    const size_t pt_bytes   = (size_t)EDGE_BLOCKS * sizeof(float);   // covers both paths
    const size_t need_super = sh_bytes + yh_bytes + pt_bytes + 16;

    if (ws_size >= need_super) {
        __half*        shadows = (__half*)d_ws;
        unsigned char* yhat    = (unsigned char*)d_ws + sh_bytes;
        float*         partial = (float*)((unsigned char*)d_ws + sh_bytes + yh_bytes);
        int*           cnt     = (int*)((unsigned char*)d_ws + sh_bytes + yh_bytes + pt_bytes);

        hipError_t ok = hipFuncSetAttribute(
            reinterpret_cast<const void*>(lap_fused),
            hipFuncAttributeMaxDynamicSharedMemorySize, DYN2);

        if (ok == hipSuccess) {
            lap_init<<<1, 64, 0, stream>>>(cnt);
            lap_fused<<<GRID, B_TH, DYN2, stream>>>(rows, cols, w, y,
                                                    shadows, yhat, partial, cnt, out);
        } else {
            // R4 pipeline (verified at 139.5 us)
            lap_degree_static<<<R_ST * S_ST, B_DEG, 0, stream>>>(rows, w, shadows);
            lap_yhat_par<<<(N_NODES + 63) / 64, B, 0, stream>>>(shadows, y, yhat, S_ST);
            lap_edge_fp8<<<EDGE_BLOCKS, B, 0, stream>>>(rows, cols, w, yhat, partial);
            lap_reduce<<<1, 1024, 0, stream>>>(partial, out);
        }
    } else {
        float* degree = (float*)d_ws;
        float* invd   = degree + N_NODES;
        hipMemsetAsync(d_out, 0, sizeof(float), stream);
        hipMemsetAsync(d_ws, 0, (size_t)N_NODES * sizeof(float), stream);
        lap_degree_kernel<<<(N_EDGES + B - 1) / B, B, 0, stream>>>(rows, w, degree);
        lap_invd_kernel<<<(N_NODES + B - 1) / B, B, 0, stream>>>(degree, invd);
        lap_edge_kernel<<<(N_EDGES + B - 1) / B, B, 0, stream>>>(rows, cols, w, y, invd, out);
    }
}

// Round 6
// 139.329 us; speedup vs baseline: 4.1661x; 4.1661x over previous
//
#include <hip/hip_runtime.h>
#include <hip/hip_fp16.h>

#define N_NODES   100000
#define N_CLASSES 16
#define N_EDGES   3200000

// ---- degree: R=3 ranges, fp32 hist, 133 KB dynamic LDS, grid 255 = 1 blk/CU ----
#define R3        3
#define NPR3      33334                 // nodes per range
#define NPR3P     33336                 // padded (float4 zeroing)
#define DYN3      (NPR3P * 4)           // 133344 B dynamic LDS
#define S3        85                    // slices -> grid 255
#define EPS3      37648                 // edges per slice (mult of 4; 85*37648 >= E)

// ---- degree fallback: static 50 KB fp32, R=8 ----
#define R_ST      8
#define NPR_ST    12500
#define S_ST      64
#define EPS_ST    50000

#define B_DEG     1024
#define KE        8                     // edges per thread, edge pass

// ===================== fp8 e4m3 helpers (verified rounds 0-5) =====================

__device__ __forceinline__ unsigned f2fp8(float f) {
    unsigned u = __float_as_uint(f);
    unsigned s = (u >> 24) & 0x80u;
    float g = fabsf(f) * 0x1p-120f;
    unsigned gu = __float_as_uint(g);
    gu += 0x7FFFFu + ((gu >> 20) & 1u);       // RNE at bit 20
    unsigned mag = gu >> 20;
    if (mag > 0x7Eu) mag = 0x7Eu;             // clamp to 448
    return s | mag;
}

__device__ __forceinline__ float fp82f(unsigned b) {
    unsigned u = ((b & 0x80u) << 24) | ((b & 0x7Fu) << 20);
    return __uint_as_float(u) * 0x1p120f;
}

#if defined(__has_builtin)
#if __has_builtin(__builtin_amdgcn_cvt_pk_f32_fp8)
#define HAVE_HW_FP8 1
#endif
#endif

#ifdef HAVE_HW_FP8
typedef float v2f __attribute__((ext_vector_type(2)));
__device__ __forceinline__ float ssd4(unsigned a, unsigned b) {
    v2f a0 = __builtin_amdgcn_cvt_pk_f32_fp8((int)a, false);
    v2f a1 = __builtin_amdgcn_cvt_pk_f32_fp8((int)a, true);
    v2f b0 = __builtin_amdgcn_cvt_pk_f32_fp8((int)b, false);
    v2f b1 = __builtin_amdgcn_cvt_pk_f32_fp8((int)b, true);
    float d0 = a0.x - b0.x;
    float d1 = a0.y - b0.y;
    float d2 = a1.x - b1.x;
    float d3 = a1.y - b1.y;
    return d0 * d0 + d1 * d1 + d2 * d2 + d3 * d3;
}
#else
__device__ __forceinline__ float ssd4(unsigned a, unsigned b) {
    float s = 0.0f;
#pragma unroll
    for (int i = 0; i < 4; ++i) {
        float va = fp82f((a >> (8 * i)) & 0xFFu);
        float vb = fp82f((b >> (8 * i)) & 0xFFu);
        float d = va - vb;
        s += d * d;
    }
    return s;
}
#endif

__device__ __forceinline__ float ssd16(uint4 A, uint4 B) {
    return ssd4(A.x, B.x) + ssd4(A.y, B.y) + ssd4(A.z, B.z) + ssd4(A.w, B.w);
}

// ===================== degree: R=3, fp32 full-LDS hist =====================
// Third structural probe of the degree pass: 133 KB fp32 histogram (native
// ds_add via atomicAdd), 85 slices, grid 255 (1 blk/CU, no tail round).
// Shadows shrink 25.6 -> 17 MB (less dirty-flush at the dispatch boundary,
// less yhat read).

__global__ __launch_bounds__(B_DEG) void lap_degree_r3(
        const int* __restrict__ rows, const float* __restrict__ w,
        __half* __restrict__ shadows, float* __restrict__ out) {
    extern __shared__ __align__(16) float hist[];
    const int b  = blockIdx.x;
    const int r  = b % R3;
    const int s  = b / R3;
    const int lo = r * NPR3;

    if (b == 0 && threadIdx.x == 0) out[0] = 0.0f;

    float4* h4 = (float4*)hist;                      // 33336 floats = 8334 float4
    for (int i = threadIdx.x; i < NPR3P / 4; i += B_DEG)
        h4[i] = make_float4(0.f, 0.f, 0.f, 0.f);
    __syncthreads();

    const int base = s * EPS3;
    for (int g = threadIdx.x; g < EPS3 / 4; g += B_DEG) {
        const int e = base + g * 4;
        if (e >= N_EDGES) continue;                  // tail slice guard
        int4   r4 = *(const int4*)(rows + e);
        float4 w4 = *(const float4*)(w + e);
        int t;
        t = r4.x - lo; if ((unsigned)t < (unsigned)NPR3) atomicAdd(&hist[t], w4.x);
        t = r4.y - lo; if ((unsigned)t < (unsigned)NPR3) atomicAdd(&hist[t], w4.y);
        t = r4.z - lo; if ((unsigned)t < (unsigned)NPR3) atomicAdd(&hist[t], w4.z);
        t = r4.w - lo; if ((unsigned)t < (unsigned)NPR3) atomicAdd(&hist[t], w4.w);
    }
    __syncthreads();

    // fp32 -> fp16 writeout, 2 nodes per store (4-B aligned: lo is even)
    __half2* dst = (__half2*)(shadows + (size_t)s * N_NODES + lo);
    for (int i2 = threadIdx.x; i2 < NPR3 / 2 + 1; i2 += B_DEG) {
        const int node = lo + 2 * i2;
        if (2 * i2 < NPR3 && node < N_NODES)
            dst[i2] = __floats2half2_rn(hist[2 * i2], hist[2 * i2 + 1]);
    }
}

// ===================== degree fallback: static 50 KB fp32, R=8 =====================

__global__ __launch_bounds__(B_DEG) void lap_degree_static(
        const int* __restrict__ rows, const float* __restrict__ w,
        __half* __restrict__ shadows, float* __restrict__ out) {
    __shared__ float hist[NPR_ST];
    const int r  = blockIdx.x & (R_ST - 1);
    const int s  = blockIdx.x >> 3;
    const int lo = r * NPR_ST;

    if (blockIdx.x == 0 && threadIdx.x == 0) out[0] = 0.0f;

    for (int i = threadIdx.x; i < NPR_ST; i += B_DEG) hist[i] = 0.0f;
    __syncthreads();

    const int base = s * EPS_ST;
    for (int g = threadIdx.x; g < EPS_ST / 4; g += B_DEG) {
        const int e = base + g * 4;
        int4   r4 = *(const int4*)(rows + e);
        float4 w4 = *(const float4*)(w + e);
        int t;
        t = r4.x - lo; if ((unsigned)t < (unsigned)NPR_ST) atomicAdd(&hist[t], w4.x);
        t = r4.y - lo; if ((unsigned)t < (unsigned)NPR_ST) atomicAdd(&hist[t], w4.y);
        t = r4.z - lo; if ((unsigned)t < (unsigned)NPR_ST) atomicAdd(&hist[t], w4.z);
        t = r4.w - lo; if ((unsigned)t < (unsigned)NPR_ST) atomicAdd(&hist[t], w4.w);
    }
    __syncthreads();

    __half* dst = shadows + (size_t)s * N_NODES + lo;
    for (int i = threadIdx.x; i < NPR_ST; i += B_DEG) dst[i] = __float2half(hist[i]);
}

// ===================== parallel shadow reduce -> rsqrt -> fp8 yhat =====================
// (byte-identical body — A/B control; S is a runtime arg, works for S=85/64)

__global__ __launch_bounds__(256) void lap_yhat_par(
        const __half* __restrict__ shadows,
        const float* __restrict__ y,
        unsigned char* __restrict__ yhat, int S) {
    const int lane = threadIdx.x & 63;
    const int wv   = threadIdx.x >> 6;
    const int n    = blockIdx.x * 64 + lane;

    float a0 = 0.0f, a1 = 0.0f, a2 = 0.0f, a3 = 0.0f;
    if (n < N_NODES) {
        const __half* p = shadows + n;
        int s = wv;
        for (; s + 12 < S; s += 16) {            // 4 independent load streams
            a0 += __half2float(p[(size_t)(s)      * N_NODES]);
            a1 += __half2float(p[(size_t)(s + 4)  * N_NODES]);
            a2 += __half2float(p[(size_t)(s + 8)  * N_NODES]);
            a3 += __half2float(p[(size_t)(s + 12) * N_NODES]);
        }
        for (; s < S; s += 4)
            a0 += __half2float(p[(size_t)s * N_NODES]);
    }

    __shared__ float sm[4][64];
    sm[wv][lane] = (a0 + a1) + (a2 + a3);
    __syncthreads();

    if (wv == 0 && n < N_NODES) {
        const float deg = (sm[0][lane] + sm[1][lane]) + (sm[2][lane] + sm[3][lane]);
        const float inv = rsqrtf(deg);
        const float4* yr = (const float4*)(y + (size_t)n * N_CLASSES);
        uint4 o;
        unsigned* op = (unsigned*)&o;
#pragma unroll
        for (int j = 0; j < 4; ++j) {
            float4 v = yr[j];
            op[j] =  f2fp8(v.x * inv)
                  | (f2fp8(v.y * inv) << 8)
                  | (f2fp8(v.z * inv) << 16)
                  | (f2fp8(v.w * inv) << 24);
        }
        *(uint4*)(yhat + (size_t)n * N_CLASSES) = o;
    }
}

// ===================== edge pass: fp8 HW decode, fused mean =====================
// R3-proven ending: per-block same-address atomicAdd measured equal to
// store+separate-reduce (R3 vs R4) -> fold the reduce dispatch away.

__global__ void lap_edge_fp8(const int* __restrict__ rows,
                             const int* __restrict__ cols,
                             const float* __restrict__ w,
                             const unsigned char* __restrict__ yhat,
                             float* __restrict__ out) {
    const int tid = blockIdx.x * blockDim.x + threadIdx.x;
    const long e0 = (long)tid * KE;
    float local = 0.0f;
    if (e0 < N_EDGES) {
        int4   ra = *(const int4*)(rows + e0);
        int4   rb = *(const int4*)(rows + e0 + 4);
        int4   ca = *(const int4*)(cols + e0);
        int4   cb = *(const int4*)(cols + e0 + 4);
        float4 wa = *(const float4*)(w + e0);
        float4 wb = *(const float4*)(w + e0 + 4);

        const int ri[KE] = {ra.x, ra.y, ra.z, ra.w, rb.x, rb.y, rb.z, rb.w};
        const int ci[KE] = {ca.x, ca.y, ca.z, ca.w, cb.x, cb.y, cb.z, cb.w};
        const float wv[KE] = {wa.x, wa.y, wa.z, wa.w, wb.x, wb.y, wb.z, wb.w};

        uint4 A[KE], B[KE];
#pragma unroll
        for (int k = 0; k < KE; ++k) {
            A[k] = *(const uint4*)(yhat + (size_t)ri[k] * N_CLASSES);
            B[k] = *(const uint4*)(yhat + (size_t)ci[k] * N_CLASSES);
        }
#pragma unroll
        for (int k = 0; k < KE; ++k)
            local += wv[k] * sqrtf(ssd16(A[k], B[k]));
    }
#pragma unroll
    for (int off = 32; off > 0; off >>= 1) local += __shfl_down(local, off, 64);
    __shared__ float sm[4];
    const int lane = threadIdx.x & 63;
    const int wid  = threadIdx.x >> 6;
    if (lane == 0) sm[wid] = local;
    __syncthreads();
    if (threadIdx.x == 0)
        atomicAdd(out, (sm[0] + sm[1] + sm[2] + sm[3]) * (1.0f / (float)N_EDGES));
}

// ===================== low fallback (tiny ws) =====================

__global__ void lap_degree_kernel(const int* __restrict__ rows,
                                  const float* __restrict__ w,
                                  float* __restrict__ degree) {
    int i = blockIdx.x * blockDim.x + threadIdx.x;
    if (i < N_EDGES) atomicAdd(&degree[rows[i]], w[i]);
}

__global__ void lap_invd_kernel(const float* __restrict__ degree,
                                float* __restrict__ invd) {
    int i = blockIdx.x * blockDim.x + threadIdx.x;
    if (i < N_NODES) invd[i] = rsqrtf(degree[i]);
}

__global__ void lap_edge_kernel(const int* __restrict__ rows,
                                const int* __restrict__ cols,
                                const float* __restrict__ w,
                                const float* __restrict__ y,
                                const float* __restrict__ invd,
                                float* __restrict__ out) {
    int i = blockIdx.x * blockDim.x + threadIdx.x;
    float local = 0.0f;
    if (i < N_EDGES) {
        int r = rows[i], c = cols[i];
        float dr = invd[r], dc = invd[c];
        const float4* yr = (const float4*)(y + (size_t)r * N_CLASSES);
        const float4* yc = (const float4*)(y + (size_t)c * N_CLASSES);
        float s = 0.0f;
#pragma unroll
        for (int j = 0; j < N_CLASSES / 4; ++j) {
            float4 a = yr[j], b = yc[j];
            float d0 = a.x * dr - b.x * dc;
            float d1 = a.y * dr - b.y * dc;
            float d2 = a.z * dr - b.z * dc;
            float d3 = a.w * dr - b.w * dc;
            s += d0 * d0 + d1 * d1 + d2 * d2 + d3 * d3;
        }
        local = w[i] * sqrtf(s);
    }
#pragma unroll
    for (int off = 32; off > 0; off >>= 1) local += __shfl_down(local, off, 64);
    __shared__ float sm[4];
    int lane = threadIdx.x & 63, wid = threadIdx.x >> 6;
    if (lane == 0) sm[wid] = local;
    __syncthreads();
    if (threadIdx.x == 0)
        atomicAdd(out, (sm[0] + sm[1] + sm[2] + sm[3]) * (1.0f / (float)N_EDGES));
}

// ===================== launch =====================

extern "C" void kernel_launch(void* const* d_in, const int* in_sizes, int n_in,
                              void* d_out, int out_size, void* d_ws, size_t ws_size,
                              hipStream_t stream) {
    const int*   edge_index = (const int*)d_in[0];   // [rows | cols]
    const float* w          = (const float*)d_in[1];
    const float* y          = (const float*)d_in[2];
    float*       out        = (float*)d_out;

    const int* rows = edge_index;
    const int* cols = edge_index + N_EDGES;
    const int  B = 256;

    // ws layout: [shadows: S3*N halves (17 MB)][yhat: N*16 fp8 (1.6 MB)]
    const size_t sh_bytes   = (size_t)S3 * N_NODES * sizeof(__half);
    const size_t need_super = sh_bytes + (size_t)N_NODES * N_CLASSES;

    const int edge_blocks = (N_EDGES / KE + B - 1) / B;   // 1563
    const int yhat_blocks = (N_NODES + 63) / 64;          // 1563

    if (ws_size >= need_super) {
        __half*        shadows = (__half*)d_ws;
        unsigned char* yhat    = (unsigned char*)d_ws + sh_bytes;

        hipError_t ok = hipFuncSetAttribute(
            reinterpret_cast<const void*>(lap_degree_r3),
            hipFuncAttributeMaxDynamicSharedMemorySize, DYN3);

        if (ok == hipSuccess) {
            lap_degree_r3<<<R3 * S3, B_DEG, DYN3, stream>>>(rows, w, shadows, out);
            lap_yhat_par<<<yhat_blocks, B, 0, stream>>>(shadows, y, yhat, S3);
        } else {
            lap_degree_static<<<R_ST * S_ST, B_DEG, 0, stream>>>(rows, w, shadows, out);
            lap_yhat_par<<<yhat_blocks, B, 0, stream>>>(shadows, y, yhat, S_ST);
        }
        lap_edge_fp8<<<edge_blocks, B, 0, stream>>>(rows, cols, w, yhat, out);
    } else {
        float* degree = (float*)d_ws;
        float* invd   = degree + N_NODES;
        hipMemsetAsync(d_out, 0, sizeof(float), stream);
        hipMemsetAsync(d_ws, 0, (size_t)N_NODES * sizeof(float), stream);
        lap_degree_kernel<<<(N_EDGES + B - 1) / B, B, 0, stream>>>(rows, w, degree);
        lap_invd_kernel<<<(N_NODES + B - 1) / B, B, 0, stream>>>(degree, invd);
        lap_edge_kernel<<<(N_EDGES + B - 1) / B, B, 0, stream>>>(rows, cols, w, y, invd, out);
    }
}

// Round 7
// 137.193 us; speedup vs baseline: 4.2310x; 1.0156x over previous
//
#include <hip/hip_runtime.h>
#include <hip/hip_fp16.h>

#define N_NODES   100000
#define N_CLASSES 16
#define N_EDGES   3200000

// ---- degree: R=3 ranges, fp32 hist, 133 KB dynamic LDS, grid 255 = 1 blk/CU ----
#define R3        3
#define NPR3      33334                 // nodes per range
#define NPR3P     33336                 // padded (float4 zeroing)
#define DYN3      (NPR3P * 4)           // 133344 B dynamic LDS
#define S3        85                    // slices -> grid 255
#define EPS3      37648                 // edges per slice (mult of 4; 85*37648 >= E)

// ---- degree fallback: static 50 KB fp32, R=8 ----
#define R_ST      8
#define NPR_ST    12500
#define S_ST      64
#define EPS_ST    50000

#define B_DEG     1024
#define KE        8                     // edges per thread, edge pass

typedef int   v4i __attribute__((ext_vector_type(4)));
typedef float v4f __attribute__((ext_vector_type(4)));

// ===================== fp8 e4m3 helpers (verified rounds 0-6) =====================

__device__ __forceinline__ unsigned f2fp8(float f) {
    unsigned u = __float_as_uint(f);
    unsigned s = (u >> 24) & 0x80u;
    float g = fabsf(f) * 0x1p-120f;
    unsigned gu = __float_as_uint(g);
    gu += 0x7FFFFu + ((gu >> 20) & 1u);       // RNE at bit 20
    unsigned mag = gu >> 20;
    if (mag > 0x7Eu) mag = 0x7Eu;             // clamp to 448
    return s | mag;
}

__device__ __forceinline__ float fp82f(unsigned b) {
    unsigned u = ((b & 0x80u) << 24) | ((b & 0x7Fu) << 20);
    return __uint_as_float(u) * 0x1p120f;
}

#if defined(__has_builtin)
#if __has_builtin(__builtin_amdgcn_cvt_pk_f32_fp8)
#define HAVE_HW_FP8 1
#endif
#endif

#ifdef HAVE_HW_FP8
typedef float v2f __attribute__((ext_vector_type(2)));
__device__ __forceinline__ float ssd4(unsigned a, unsigned b) {
    v2f a0 = __builtin_amdgcn_cvt_pk_f32_fp8((int)a, false);
    v2f a1 = __builtin_amdgcn_cvt_pk_f32_fp8((int)a, true);
    v2f b0 = __builtin_amdgcn_cvt_pk_f32_fp8((int)b, false);
    v2f b1 = __builtin_amdgcn_cvt_pk_f32_fp8((int)b, true);
    float d0 = a0.x - b0.x;
    float d1 = a0.y - b0.y;
    float d2 = a1.x - b1.x;
    float d3 = a1.y - b1.y;
    return d0 * d0 + d1 * d1 + d2 * d2 + d3 * d3;
}
#else
__device__ __forceinline__ float ssd4(unsigned a, unsigned b) {
    float s = 0.0f;
#pragma unroll
    for (int i = 0; i < 4; ++i) {
        float va = fp82f((a >> (8 * i)) & 0xFFu);
        float vb = fp82f((b >> (8 * i)) & 0xFFu);
        float d = va - vb;
        s += d * d;
    }
    return s;
}
#endif

__device__ __forceinline__ float ssd16(uint4 A, uint4 B) {
    return ssd4(A.x, B.x) + ssd4(A.y, B.y) + ssd4(A.z, B.z) + ssd4(A.w, B.w);
}

// ===================== degree: R=3, fp32 full-LDS hist =====================
// (byte-identical to round-6 — A/B control)

__global__ __launch_bounds__(B_DEG) void lap_degree_r3(
        const int* __restrict__ rows, const float* __restrict__ w,
        __half* __restrict__ shadows, float* __restrict__ out) {
    extern __shared__ __align__(16) float hist[];
    const int b  = blockIdx.x;
    const int r  = b % R3;
    const int s  = b / R3;
    const int lo = r * NPR3;

    if (b == 0 && threadIdx.x == 0) out[0] = 0.0f;

    float4* h4 = (float4*)hist;                      // 33336 floats = 8334 float4
    for (int i = threadIdx.x; i < NPR3P / 4; i += B_DEG)
        h4[i] = make_float4(0.f, 0.f, 0.f, 0.f);
    __syncthreads();

    const int base = s * EPS3;
    for (int g = threadIdx.x; g < EPS3 / 4; g += B_DEG) {
        const int e = base + g * 4;
        if (e >= N_EDGES) continue;                  // tail slice guard
        int4   r4 = *(const int4*)(rows + e);
        float4 w4 = *(const float4*)(w + e);
        int t;
        t = r4.x - lo; if ((unsigned)t < (unsigned)NPR3) atomicAdd(&hist[t], w4.x);
        t = r4.y - lo; if ((unsigned)t < (unsigned)NPR3) atomicAdd(&hist[t], w4.y);
        t = r4.z - lo; if ((unsigned)t < (unsigned)NPR3) atomicAdd(&hist[t], w4.z);
        t = r4.w - lo; if ((unsigned)t < (unsigned)NPR3) atomicAdd(&hist[t], w4.w);
    }
    __syncthreads();

    // fp32 -> fp16 writeout, 2 nodes per store (4-B aligned: lo is even)
    __half2* dst = (__half2*)(shadows + (size_t)s * N_NODES + lo);
    for (int i2 = threadIdx.x; i2 < NPR3 / 2 + 1; i2 += B_DEG) {
        const int node = lo + 2 * i2;
        if (2 * i2 < NPR3 && node < N_NODES)
            dst[i2] = __floats2half2_rn(hist[2 * i2], hist[2 * i2 + 1]);
    }
}

// ===================== degree fallback: static 50 KB fp32, R=8 =====================

__global__ __launch_bounds__(B_DEG) void lap_degree_static(
        const int* __restrict__ rows, const float* __restrict__ w,
        __half* __restrict__ shadows, float* __restrict__ out) {
    __shared__ float hist[NPR_ST];
    const int r  = blockIdx.x & (R_ST - 1);
    const int s  = blockIdx.x >> 3;
    const int lo = r * NPR_ST;

    if (blockIdx.x == 0 && threadIdx.x == 0) out[0] = 0.0f;

    for (int i = threadIdx.x; i < NPR_ST; i += B_DEG) hist[i] = 0.0f;
    __syncthreads();

    const int base = s * EPS_ST;
    for (int g = threadIdx.x; g < EPS_ST / 4; g += B_DEG) {
        const int e = base + g * 4;
        int4   r4 = *(const int4*)(rows + e);
        float4 w4 = *(const float4*)(w + e);
        int t;
        t = r4.x - lo; if ((unsigned)t < (unsigned)NPR_ST) atomicAdd(&hist[t], w4.x);
        t = r4.y - lo; if ((unsigned)t < (unsigned)NPR_ST) atomicAdd(&hist[t], w4.y);
        t = r4.z - lo; if ((unsigned)t < (unsigned)NPR_ST) atomicAdd(&hist[t], w4.z);
        t = r4.w - lo; if ((unsigned)t < (unsigned)NPR_ST) atomicAdd(&hist[t], w4.w);
    }
    __syncthreads();

    __half* dst = shadows + (size_t)s * N_NODES + lo;
    for (int i = threadIdx.x; i < NPR_ST; i += B_DEG) dst[i] = __float2half(hist[i]);
}

// ===================== parallel shadow reduce -> rsqrt -> fp8 yhat =====================
// (byte-identical — A/B control)

__global__ __launch_bounds__(256) void lap_yhat_par(
        const __half* __restrict__ shadows,
        const float* __restrict__ y,
        unsigned char* __restrict__ yhat, int S) {
    const int lane = threadIdx.x & 63;
    const int wv   = threadIdx.x >> 6;
    const int n    = blockIdx.x * 64 + lane;

    float a0 = 0.0f, a1 = 0.0f, a2 = 0.0f, a3 = 0.0f;
    if (n < N_NODES) {
        const __half* p = shadows + n;
        int s = wv;
        for (; s + 12 < S; s += 16) {            // 4 independent load streams
            a0 += __half2float(p[(size_t)(s)      * N_NODES]);
            a1 += __half2float(p[(size_t)(s + 4)  * N_NODES]);
            a2 += __half2float(p[(size_t)(s + 8)  * N_NODES]);
            a3 += __half2float(p[(size_t)(s + 12) * N_NODES]);
        }
        for (; s < S; s += 4)
            a0 += __half2float(p[(size_t)s * N_NODES]);
    }

    __shared__ float sm[4][64];
    sm[wv][lane] = (a0 + a1) + (a2 + a3);
    __syncthreads();

    if (wv == 0 && n < N_NODES) {
        const float deg = (sm[0][lane] + sm[1][lane]) + (sm[2][lane] + sm[3][lane]);
        const float inv = rsqrtf(deg);
        const float4* yr = (const float4*)(y + (size_t)n * N_CLASSES);
        uint4 o;
        unsigned* op = (unsigned*)&o;
#pragma unroll
        for (int j = 0; j < 4; ++j) {
            float4 v = yr[j];
            op[j] =  f2fp8(v.x * inv)
                  | (f2fp8(v.y * inv) << 8)
                  | (f2fp8(v.z * inv) << 16)
                  | (f2fp8(v.w * inv) << 24);
        }
        *(uint4*)(yhat + (size_t)n * N_CLASSES) = o;
    }
}

// ===================== edge pass v2: nt streams + capped VGPR =====================
// Changes this round (edge ONLY):
//  (1) rows/cols/w stream loads are NON-TEMPORAL: 38.4 MB of streams no longer
//      evict the 1.6 MB yhat table from the per-XCD L2s -> gathers stay L2-hit.
//  (2) __launch_bounds__(256, 4): cap 128 VGPR -> >=4 waves/SIMD for gather
//      latency hiding.
// Compute body and gather pattern unchanged.

__global__ __launch_bounds__(256, 4) void lap_edge_fp8(
        const int* __restrict__ rows,
        const int* __restrict__ cols,
        const float* __restrict__ w,
        const unsigned char* __restrict__ yhat,
        float* __restrict__ out) {
    const int tid = blockIdx.x * blockDim.x + threadIdx.x;
    const long e0 = (long)tid * KE;
    float local = 0.0f;
    if (e0 < N_EDGES) {
        v4i ra = __builtin_nontemporal_load((const v4i*)(rows + e0));
        v4i rb = __builtin_nontemporal_load((const v4i*)(rows + e0 + 4));
        v4i ca = __builtin_nontemporal_load((const v4i*)(cols + e0));
        v4i cb = __builtin_nontemporal_load((const v4i*)(cols + e0 + 4));
        v4f wa = __builtin_nontemporal_load((const v4f*)(w + e0));
        v4f wb = __builtin_nontemporal_load((const v4f*)(w + e0 + 4));

        const int ri[KE] = {ra.x, ra.y, ra.z, ra.w, rb.x, rb.y, rb.z, rb.w};
        const int ci[KE] = {ca.x, ca.y, ca.z, ca.w, cb.x, cb.y, cb.z, cb.w};
        const float wv[KE] = {wa.x, wa.y, wa.z, wa.w, wb.x, wb.y, wb.z, wb.w};

        uint4 A[KE], B[KE];
#pragma unroll
        for (int k = 0; k < KE; ++k) {
            A[k] = *(const uint4*)(yhat + (size_t)ri[k] * N_CLASSES);
            B[k] = *(const uint4*)(yhat + (size_t)ci[k] * N_CLASSES);
        }
#pragma unroll
        for (int k = 0; k < KE; ++k)
            local += wv[k] * sqrtf(ssd16(A[k], B[k]));
    }
#pragma unroll
    for (int off = 32; off > 0; off >>= 1) local += __shfl_down(local, off, 64);
    __shared__ float sm[4];
    const int lane = threadIdx.x & 63;
    const int wid  = threadIdx.x >> 6;
    if (lane == 0) sm[wid] = local;
    __syncthreads();
    if (threadIdx.x == 0)
        atomicAdd(out, (sm[0] + sm[1] + sm[2] + sm[3]) * (1.0f / (float)N_EDGES));
}

// ===================== low fallback (tiny ws) =====================

__global__ void lap_degree_kernel(const int* __restrict__ rows,
                                  const float* __restrict__ w,
                                  float* __restrict__ degree) {
    int i = blockIdx.x * blockDim.x + threadIdx.x;
    if (i < N_EDGES) atomicAdd(&degree[rows[i]], w[i]);
}

__global__ void lap_invd_kernel(const float* __restrict__ degree,
                                float* __restrict__ invd) {
    int i = blockIdx.x * blockDim.x + threadIdx.x;
    if (i < N_NODES) invd[i] = rsqrtf(degree[i]);
}

__global__ void lap_edge_kernel(const int* __restrict__ rows,
                                const int* __restrict__ cols,
                                const float* __restrict__ w,
                                const float* __restrict__ y,
                                const float* __restrict__ invd,
                                float* __restrict__ out) {
    int i = blockIdx.x * blockDim.x + threadIdx.x;
    float local = 0.0f;
    if (i < N_EDGES) {
        int r = rows[i], c = cols[i];
        float dr = invd[r], dc = invd[c];
        const float4* yr = (const float4*)(y + (size_t)r * N_CLASSES);
        const float4* yc = (const float4*)(y + (size_t)c * N_CLASSES);
        float s = 0.0f;
#pragma unroll
        for (int j = 0; j < N_CLASSES / 4; ++j) {
            float4 a = yr[j], b = yc[j];
            float d0 = a.x * dr - b.x * dc;
            float d1 = a.y * dr - b.y * dc;
            float d2 = a.z * dr - b.z * dc;
            float d3 = a.w * dr - b.w * dc;
            s += d0 * d0 + d1 * d1 + d2 * d2 + d3 * d3;
        }
        local = w[i] * sqrtf(s);
    }
#pragma unroll
    for (int off = 32; off > 0; off >>= 1) local += __shfl_down(local, off, 64);
    __shared__ float sm[4];
    int lane = threadIdx.x & 63, wid = threadIdx.x >> 6;
    if (lane == 0) sm[wid] = local;
    __syncthreads();
    if (threadIdx.x == 0)
        atomicAdd(out, (sm[0] + sm[1] + sm[2] + sm[3]) * (1.0f / (float)N_EDGES));
}

// ===================== launch =====================

extern "C" void kernel_launch(void* const* d_in, const int* in_sizes, int n_in,
                              void* d_out, int out_size, void* d_ws, size_t ws_size,
                              hipStream_t stream) {
    const int*   edge_index = (const int*)d_in[0];   // [rows | cols]
    const float* w          = (const float*)d_in[1];
    const float* y          = (const float*)d_in[2];
    float*       out        = (float*)d_out;

    const int* rows = edge_index;
    const int* cols = edge_index + N_EDGES;
    const int  B = 256;

    // ws layout: [shadows: S3*N halves (17 MB)][yhat: N*16 fp8 (1.6 MB)]
    const size_t sh_bytes   = (size_t)S3 * N_NODES * sizeof(__half);
    const size_t need_super = sh_bytes + (size_t)N_NODES * N_CLASSES;

    const int edge_blocks = (N_EDGES / KE + B - 1) / B;   // 1563
    const int yhat_blocks = (N_NODES + 63) / 64;          // 1563

    if (ws_size >= need_super) {
        __half*        shadows = (__half*)d_ws;
        unsigned char* yhat    = (unsigned char*)d_ws + sh_bytes;

        hipError_t ok = hipFuncSetAttribute(
            reinterpret_cast<const void*>(lap_degree_r3),
            hipFuncAttributeMaxDynamicSharedMemorySize, DYN3);

        if (ok == hipSuccess) {
            lap_degree_r3<<<R3 * S3, B_DEG, DYN3, stream>>>(rows, w, shadows, out);
            lap_yhat_par<<<yhat_blocks, B, 0, stream>>>(shadows, y, yhat, S3);
        } else {
            lap_degree_static<<<R_ST * S_ST, B_DEG, 0, stream>>>(rows, w, shadows, out);
            lap_yhat_par<<<yhat_blocks, B, 0, stream>>>(shadows, y, yhat, S_ST);
        }
        lap_edge_fp8<<<edge_blocks, B, 0, stream>>>(rows, cols, w, yhat, out);
    } else {
        float* degree = (float*)d_ws;
        float* invd   = degree + N_NODES;
        hipMemsetAsync(d_out, 0, sizeof(float), stream);
        hipMemsetAsync(d_ws, 0, (size_t)N_NODES * sizeof(float), stream);
        lap_degree_kernel<<<(N_EDGES + B - 1) / B, B, 0, stream>>>(rows, w, degree);
        lap_invd_kernel<<<(N_NODES + B - 1) / B, B, 0, stream>>>(degree, invd);
        lap_edge_kernel<<<(N_EDGES + B - 1) / B, B, 0, stream>>>(rows, cols, w, y, invd, out);
    }
}